// Round 6
// baseline (65.016 us; speedup 1.0000x reference)
//
#include <hip/hip_runtime.h>

// RoIPool exactly matching the JAX reference:
//   x1 = (int)(W * box.x) (f32 mul, trunc); sw = (x2-x1)/POOL (int div)
//   out[b,n,i,j,c] = max over s<sh, t<sw of fm[b, y1+i*sh+s, x1+j*sw+t, c]
// B=2, N=128, H=W=50, C=256, POOL=7; sh,sw in [1,4] by construction.
//
// Wave-uniformity made EXPLICIT via readfirstlane: each wave (64 lanes)
// serves one (b,n,i,j) cell's 256 channels. Cell id, box coords, sh/sw,
// and the cell base offset are forced into SGPRs, so:
//   - box fetch   -> one scalar load per wave (not 4 per-lane VMEM loads)
//   - (sh,sw) switch -> scalar branch (no exec-mask divergence cascade)
//   - data loads  -> scalar base + (lane*16) voffset + imm offset
// Exactly SH*SW independent float4 loads per thread, no masks, no clamps
// (clipping provably identity: 7*sw <= x2-x1, x2 <= 50). Generic clamped
// fallback retained for out-of-range boxes (dead for this distribution).

#define POOLP 7
#define NROIS 128
#define HH 50
#define WW 50
#define CC 256

template <int SH, int SW>
__device__ __forceinline__ float4 cell_max(const char* __restrict__ cellp,
                                           int lane_byte) {
    float4 v[SH][SW];
#pragma unroll
    for (int s = 0; s < SH; ++s) {
#pragma unroll
        for (int t = 0; t < SW; ++t) {
            v[s][t] = *reinterpret_cast<const float4*>(
                cellp + (size_t)((s * WW + t) * (CC * 4)) + lane_byte);
        }
    }
    float4 m = v[0][0];
#pragma unroll
    for (int s = 0; s < SH; ++s) {
#pragma unroll
        for (int t = 0; t < SW; ++t) {
            if (s == 0 && t == 0) continue;
            m.x = fmaxf(m.x, v[s][t].x);
            m.y = fmaxf(m.y, v[s][t].y);
            m.z = fmaxf(m.z, v[s][t].z);
            m.w = fmaxf(m.w, v[s][t].w);
        }
    }
    return m;
}

__global__ __launch_bounds__(256) void roipool_kernel(
    const float* __restrict__ fm,   // [B,H,W,C]
    const float* __restrict__ rpn,  // [B,N,4]
    float* __restrict__ out)        // [B,N,P,P,C]
{
    // Wave-uniform cell id, forced scalar.
    int wid  = __builtin_amdgcn_readfirstlane((int)(threadIdx.x >> 6)); // 0..3
    int lane = threadIdx.x & 63;
    int cell = blockIdx.x * 4 + wid;          // (b,n,i,j) flattened, SGPR

    int j   = cell % POOLP;
    int t1  = cell / POOLP;
    int i   = t1 % POOLP;
    int bn  = t1 / POOLP;                     // b*N + n
    int b   = bn >> 7;                        // NROIS = 128

    // Scalar box fetch (uniform address -> s_load).
    float4 boxv = *reinterpret_cast<const float4*>(rpn + (bn << 2));
    // f32 mul + trunc happen on VALU; pin results back to SGPRs.
    int x1 = __builtin_amdgcn_readfirstlane((int)(WW * boxv.x));
    int y1 = __builtin_amdgcn_readfirstlane((int)(HH * boxv.y));
    int x2 = __builtin_amdgcn_readfirstlane((int)(WW * boxv.z));
    int y2 = __builtin_amdgcn_readfirstlane((int)(HH * boxv.w));

    int sw = (x2 - x1) / POOLP;               // all scalar from here
    int sh = (y2 - y1) / POOLP;
    int rowbase = y1 + i * sh;
    int colbase = x1 + j * sw;

    int lane_byte = lane << 4;
    float4 m;

    if (sh >= 1 && sh <= 4 && sw >= 1 && sw <= 4) {
        unsigned off = (unsigned)((b * HH + rowbase) * WW + colbase) * (CC * 4u);
        const char* cellp = reinterpret_cast<const char*>(fm) + off;
        int code = ((sh - 1) << 2) | (sw - 1);  // uniform -> scalar branch
        switch (code) {
            case  0: m = cell_max<1, 1>(cellp, lane_byte); break;
            case  1: m = cell_max<1, 2>(cellp, lane_byte); break;
            case  2: m = cell_max<1, 3>(cellp, lane_byte); break;
            case  3: m = cell_max<1, 4>(cellp, lane_byte); break;
            case  4: m = cell_max<2, 1>(cellp, lane_byte); break;
            case  5: m = cell_max<2, 2>(cellp, lane_byte); break;
            case  6: m = cell_max<2, 3>(cellp, lane_byte); break;
            case  7: m = cell_max<2, 4>(cellp, lane_byte); break;
            case  8: m = cell_max<3, 1>(cellp, lane_byte); break;
            case  9: m = cell_max<3, 2>(cellp, lane_byte); break;
            case 10: m = cell_max<3, 3>(cellp, lane_byte); break;
            case 11: m = cell_max<3, 4>(cellp, lane_byte); break;
            case 12: m = cell_max<4, 1>(cellp, lane_byte); break;
            case 13: m = cell_max<4, 2>(cellp, lane_byte); break;
            case 14: m = cell_max<4, 3>(cellp, lane_byte); break;
            default: m = cell_max<4, 4>(cellp, lane_byte); break;
        }
    } else {
        // Generic clamped fallback (reference semantics for any box).
        const float NEG_INF = -__builtin_inff();
        m = make_float4(NEG_INF, NEG_INF, NEG_INF, NEG_INF);
        const float* fbase = fm + (size_t)b * (HH * WW * CC) + (size_t)(lane << 2);
        for (int s = 0; s < sh; ++s) {
            int row = min(max(rowbase + s, 0), HH - 1);
            const float* rowp = fbase + (size_t)row * (WW * CC);
            for (int t = 0; t < sw; ++t) {
                int col = min(max(colbase + t, 0), WW - 1);
                float4 v = *reinterpret_cast<const float4*>(rowp + (size_t)col * CC);
                m.x = fmaxf(m.x, v.x);
                m.y = fmaxf(m.y, v.y);
                m.z = fmaxf(m.z, v.z);
                m.w = fmaxf(m.w, v.w);
            }
        }
    }

    reinterpret_cast<float4*>(out)[((size_t)cell << 6) + lane] = m;
}

extern "C" void kernel_launch(void* const* d_in, const int* in_sizes, int n_in,
                              void* d_out, int out_size, void* d_ws, size_t ws_size,
                              hipStream_t stream) {
    const float* fm  = (const float*)d_in[0];
    const float* rpn = (const float*)d_in[1];
    float* out = (float*)d_out;

    const int total = 2 * NROIS * POOLP * POOLP * 64;  // 802,816 threads
    const int block = 256;
    const int grid = total / block;                    // 3136 blocks, 4 waves each
    roipool_kernel<<<grid, block, 0, stream>>>(fm, rpn, out);
}

// Round 7
// 64.538 us; speedup vs baseline: 1.0074x; 1.0074x over previous
//
#include <hip/hip_runtime.h>

// RoIPool exactly matching the JAX reference:
//   x1 = (int)(W * box.x) (f32 mul, trunc); sw = (x2-x1)/POOL (int div)
//   out[b,n,i,j,c] = max over s<sh, t<sw of fm[b, y1+i*sh+s, x1+j*sw+t, c]
// B=2, N=128, H=W=50, C=256, POOL=7; sh,sw in [1,4] by construction.
//
// One wave = one (b,n,i,j) cell's 256 channels (lane -> 4 channels).
// Static (SH,SW)-specialized paths via wave-uniform scalar switch; loads
// row-batched so <=8 float4 are in flight per thread (<=32 data VGPRs),
// and __launch_bounds__(256,8) pins the allocator to <=64 VGPR so 8
// waves/SIMD stay resident — the kernel is cold-L2 latency-bound (the
// harness's 268MB ws-poison fill thrashes L2 before every timed launch),
// so residency x in-flight loads is the lever.

#define POOLP 7
#define NROIS 128
#define HH 50
#define WW 50
#define CC 256
#define ROWBYTES (WW * CC * 4)   // 51200
#define COLBYTES (CC * 4)        // 1024

__device__ __forceinline__ float4 max4(float4 a, float4 b) {
    return make_float4(fmaxf(a.x, b.x), fmaxf(a.y, b.y),
                       fmaxf(a.z, b.z), fmaxf(a.w, b.w));
}

// Max over NR full rows x SW cols; NR*SW <= 8 loads in flight.
template <int NR, int SW>
__device__ __forceinline__ float4 rows_max(const char* __restrict__ p,
                                           int lane_byte) {
    float4 v[NR][SW];
#pragma unroll
    for (int s = 0; s < NR; ++s)
#pragma unroll
        for (int t = 0; t < SW; ++t)
            v[s][t] = *reinterpret_cast<const float4*>(
                p + (size_t)s * ROWBYTES + (size_t)t * COLBYTES + lane_byte);
    float4 m = v[0][0];
#pragma unroll
    for (int s = 0; s < NR; ++s)
#pragma unroll
        for (int t = 0; t < SW; ++t) {
            if (s == 0 && t == 0) continue;
            m = max4(m, v[s][t]);
        }
    return m;
}

template <int SH, int SW>
__device__ __forceinline__ float4 cell_max(const char* __restrict__ p,
                                           int lane_byte) {
    constexpr int RB = (SH * SW <= 8) ? SH : ((8 / SW) < 1 ? 1 : (8 / SW));
    float4 m = rows_max<RB, SW>(p, lane_byte);
    if constexpr (SH > RB)
        m = max4(m, cell_max<SH - RB, SW>(p + (size_t)RB * ROWBYTES, lane_byte));
    return m;
}

__global__ __launch_bounds__(256, 8) void roipool_kernel(
    const float* __restrict__ fm,   // [B,H,W,C]
    const float* __restrict__ rpn,  // [B,N,4]
    float* __restrict__ out)        // [B,N,P,P,C]
{
    int wid  = __builtin_amdgcn_readfirstlane((int)(threadIdx.x >> 6)); // 0..3
    int lane = threadIdx.x & 63;
    int cell = blockIdx.x * 4 + wid;          // (b,n,i,j) flattened, SGPR

    int j   = cell % POOLP;
    int t1  = cell / POOLP;
    int i   = t1 % POOLP;
    int bn  = t1 / POOLP;                     // b*N + n
    int b   = bn >> 7;                        // NROIS = 128

    float4 boxv = *reinterpret_cast<const float4*>(rpn + (bn << 2));
    int x1 = __builtin_amdgcn_readfirstlane((int)(WW * boxv.x));
    int y1 = __builtin_amdgcn_readfirstlane((int)(HH * boxv.y));
    int x2 = __builtin_amdgcn_readfirstlane((int)(WW * boxv.z));
    int y2 = __builtin_amdgcn_readfirstlane((int)(HH * boxv.w));

    int sw = (x2 - x1) / POOLP;               // scalar from here
    int sh = (y2 - y1) / POOLP;
    int rowbase = y1 + i * sh;
    int colbase = x1 + j * sw;

    int lane_byte = lane << 4;
    float4 m;

    if (sh >= 1 && sh <= 4 && sw >= 1 && sw <= 4) {
        unsigned off = (unsigned)((b * HH + rowbase) * WW + colbase) * (unsigned)COLBYTES;
        const char* cellp = reinterpret_cast<const char*>(fm) + off;
        int code = ((sh - 1) << 2) | (sw - 1);  // uniform -> scalar branch
        switch (code) {
            case  0: m = cell_max<1, 1>(cellp, lane_byte); break;
            case  1: m = cell_max<1, 2>(cellp, lane_byte); break;
            case  2: m = cell_max<1, 3>(cellp, lane_byte); break;
            case  3: m = cell_max<1, 4>(cellp, lane_byte); break;
            case  4: m = cell_max<2, 1>(cellp, lane_byte); break;
            case  5: m = cell_max<2, 2>(cellp, lane_byte); break;
            case  6: m = cell_max<2, 3>(cellp, lane_byte); break;
            case  7: m = cell_max<2, 4>(cellp, lane_byte); break;
            case  8: m = cell_max<3, 1>(cellp, lane_byte); break;
            case  9: m = cell_max<3, 2>(cellp, lane_byte); break;
            case 10: m = cell_max<3, 3>(cellp, lane_byte); break;
            case 11: m = cell_max<3, 4>(cellp, lane_byte); break;
            case 12: m = cell_max<4, 1>(cellp, lane_byte); break;
            case 13: m = cell_max<4, 2>(cellp, lane_byte); break;
            case 14: m = cell_max<4, 3>(cellp, lane_byte); break;
            default: m = cell_max<4, 4>(cellp, lane_byte); break;
        }
    } else {
        // Generic clamped fallback (reference semantics for any box).
        const float NEG_INF = -__builtin_inff();
        m = make_float4(NEG_INF, NEG_INF, NEG_INF, NEG_INF);
        const float* fbase = fm + (size_t)b * (HH * WW * CC) + (size_t)(lane << 2);
        for (int s = 0; s < sh; ++s) {
            int row = min(max(rowbase + s, 0), HH - 1);
            const float* rowp = fbase + (size_t)row * (WW * CC);
            for (int t = 0; t < sw; ++t) {
                int col = min(max(colbase + t, 0), WW - 1);
                float4 v = *reinterpret_cast<const float4*>(rowp + (size_t)col * CC);
                m = max4(m, v);
            }
        }
    }

    reinterpret_cast<float4*>(out)[((size_t)cell << 6) + lane] = m;
}

extern "C" void kernel_launch(void* const* d_in, const int* in_sizes, int n_in,
                              void* d_out, int out_size, void* d_ws, size_t ws_size,
                              hipStream_t stream) {
    const float* fm  = (const float*)d_in[0];
    const float* rpn = (const float*)d_in[1];
    float* out = (float*)d_out;

    const int total = 2 * NROIS * POOLP * POOLP * 64;  // 802,816 threads
    const int block = 256;
    const int grid = total / block;                    // 3136 blocks, 4 waves each
    roipool_kernel<<<grid, block, 0, stream>>>(fm, rpn, out);
}